// Round 13
// baseline (56.481 us; speedup 1.0000x reference)
//
#include <hip/hip_runtime.h>
#include <hip/hip_fp16.h>

// NCC (local normalized cross-correlation) loss, 9x9x9 window, zero-pad.
// Volume: [1,1,128,160,192] f32. Output: scalar f32 = 1 - mean(cc).
//
// R13: two-kernel structure, A intermediate eliminated.
//  K12 (fused W+H sums): block = (d, h-chunk of 40, w-chunk of 32 pairs).
//     Stage I/J tile + halos in LDS (48 rows x 72 f32 x 2 = 27.6 KB, clean
//     float2 masked loads). Each thread (wp, hslot): W-row-sums of all 5
//     channels from aligned ds_read_b64 taps (f32 math), packed to
//     uint4+u32; run of 5 outputs via static 4-deep fifo; S kept in pk-fp16
//     (proven R11 pass2). Writes B only: I/J amp 1.35x, A's 114MB gone.
//  pass3: D-axis reload+FIFO + cc + reduce (R12, pp-major XCD swizzle)
//     + fused finalize via ordered ticket (consumed atomic return, no fence).
// Layout per pixel-pair: ch0..3 = uint4 (4x half2), ch4 = u32.
// ws: Bq 31.5MB | Bs 7.9MB | acc | ctr.

#define D_ 128
#define H_ 160
#define W_ 192
#define WP_ (W_ / 2)               // 96 pairs per line
#define HW_ (H_ * W_)
#define HWP_ (HW_ / 2)             // 15360 pairs per d-slice
#define N_ (D_ * H_ * W_)
#define NP_ (N_ / 2)               // 1,966,080 pairs total
#define WIN_INV (1.0f / 729.0f)
#define CH3 8                      // d-run length in pass3
#define NBLK12 (D_ * 4 * 3)        // 1536
#define NBLK3 ((HWP_ / 256) * (D_ / CH3))      // 960
#define NXCD 8

union U32H2 { unsigned u; __half2 h; };
__device__ __forceinline__ __half2 u2h(unsigned u) { U32H2 x; x.u = u; return x.h; }
__device__ __forceinline__ unsigned h2u(__half2 h) { U32H2 x; x.h = h; return x.u; }
__device__ __forceinline__ unsigned pack2(float x, float y) {
    return h2u(__float22half2_rn(make_float2(x, y)));
}
__device__ __forceinline__ float2 unpack2(unsigned u) {
    return __half22float2(u2h(u));
}

__device__ __forceinline__ void addU(float2 S[5], const uint4& q, unsigned sv) {
    float2 v0 = unpack2(q.x), v1 = unpack2(q.y), v2 = unpack2(q.z),
           v3 = unpack2(q.w), v4 = unpack2(sv);
    S[0].x += v0.x; S[0].y += v0.y;
    S[1].x += v1.x; S[1].y += v1.y;
    S[2].x += v2.x; S[2].y += v2.y;
    S[3].x += v3.x; S[3].y += v3.y;
    S[4].x += v4.x; S[4].y += v4.y;
}
__device__ __forceinline__ void subU(float2 S[5], const uint4& q, unsigned sv) {
    float2 v0 = unpack2(q.x), v1 = unpack2(q.y), v2 = unpack2(q.z),
           v3 = unpack2(q.w), v4 = unpack2(sv);
    S[0].x -= v0.x; S[0].y -= v0.y;
    S[1].x -= v1.x; S[1].y -= v1.y;
    S[2].x -= v2.x; S[2].y -= v2.y;
    S[3].x -= v3.x; S[3].y -= v3.y;
    S[4].x -= v4.x; S[4].y -= v4.y;
}

// ---------------- K12: fused W-sum + H-sum -> packed B ---------------------
__global__ __launch_bounds__(256) void ncc_k12(const float* __restrict__ I,
                                               const float* __restrict__ J,
                                               uint4* __restrict__ Bq,
                                               unsigned* __restrict__ Bs,
                                               float* __restrict__ acc,
                                               unsigned* __restrict__ ctr) {
    __shared__ float sI[48][72];               // 13.8 KB
    __shared__ float sJ[48][72];               // 13.8 KB
    if (blockIdx.x == 0 && threadIdx.x == 0) { *acc = 0.0f; *ctr = 0u; }
    // chunked XCD swizzle (1536 % 8 == 0): 192 consecutive per XCD
    const int orig = (blockIdx.x & 7) * (NBLK12 / NXCD) + (blockIdx.x >> 3);
    const int d  = orig / 12;
    const int hc = (orig / 3) & 3;
    const int wc = orig % 3;
    const int h0 = hc * 40;
    const int wbase = wc * 64;                 // f32 units
    const float* Ib = I + (size_t)d * HW_;
    const float* Jb = J + (size_t)d * HW_;

    // stage 48 rows x 36 float2 per array; full-float2 masks (w always even)
    for (int i = threadIdx.x; i < 48 * 36; i += 256) {
        const int r = i / 36, c2 = i % 36;
        const int h = h0 - 4 + r;
        const int w = wbase - 4 + 2 * c2;
        float2 vi = make_float2(0.f, 0.f), vj = make_float2(0.f, 0.f);
        if ((unsigned)h < (unsigned)H_ && (unsigned)w < (unsigned)(W_ - 1)) {
            vi = *(const float2*)(Ib + h * W_ + w);
            vj = *(const float2*)(Jb + h * W_ + w);
        }
        sI[r][2 * c2] = vi.x; sI[r][2 * c2 + 1] = vi.y;
        sJ[r][2 * c2] = vj.x; sJ[r][2 * c2 + 1] = vj.y;
    }
    __syncthreads();

    const int wp = threadIdx.x & 31;           // 0..31
    const int hslot = threadIdx.x >> 5;        // 0..7 (run of 5 rows each)
    const int rb = hslot * 5;                  // local row base (warm row 0)

    // W-row-sum of all 5 channels at local row r -> packed (q, sv)
    auto rowsum = [&](int r, uint4& q, unsigned& sv) {
        const float* ri = &sI[r][2 * wp];      // taps: 10 contiguous f32
        const float* rj = &sJ[r][2 * wp];
        float a[10], b[10];
#pragma unroll
        for (int k = 0; k < 5; ++k) {
            float2 va = *(const float2*)(ri + 2 * k);
            float2 vb = *(const float2*)(rj + 2 * k);
            a[2 * k] = va.x; a[2 * k + 1] = va.y;
            b[2 * k] = vb.x; b[2 * k + 1] = vb.y;
        }
        float s1 = 0, s2 = 0, s3 = 0, s4 = 0, s5 = 0;
#pragma unroll
        for (int k = 0; k < 9; ++k) {
            s1 += a[k]; s2 += b[k];
            s3 += a[k] * a[k]; s4 += b[k] * b[k]; s5 += a[k] * b[k];
        }
        const float t1 = s1 - a[0] + a[9];
        const float t2 = s2 - b[0] + b[9];
        const float t3 = s3 - a[0] * a[0] + a[9] * a[9];
        const float t4 = s4 - b[0] * b[0] + b[9] * b[9];
        const float t5 = s5 - a[0] * b[0] + a[9] * b[9];
        q = make_uint4(pack2(s1, t1), pack2(s2, t2), pack2(s3, t3), pack2(s4, t4));
        sv = pack2(s5, t5);
    };

    // warm-up rows rb..rb+8; keep first 4 (the ones later subtracted)
    uint4 w0q, w1q, w2q, w3q; unsigned w0s, w1s, w2s, w3s;
    const __half2 z = __float2half2_rn(0.f);
    __half2 S0 = z, S1 = z, S2 = z, S3 = z, S4 = z;
    {
        uint4 q; unsigned sv;
#pragma unroll
        for (int j = 0; j < 9; ++j) {
            rowsum(rb + j, q, sv);
            if (j == 0) { w0q = q; w0s = sv; }
            if (j == 1) { w1q = q; w1s = sv; }
            if (j == 2) { w2q = q; w2s = sv; }
            if (j == 3) { w3q = q; w3s = sv; }
            S0 = __hadd2(S0, u2h(q.x)); S1 = __hadd2(S1, u2h(q.y));
            S2 = __hadd2(S2, u2h(q.z)); S3 = __hadd2(S3, u2h(q.w));
            S4 = __hadd2(S4, u2h(sv));
        }
    }

    const int wpg = wc * 32 + wp;
    const size_t ob0 = (size_t)d * (H_ * WP_) + (size_t)(h0 + rb) * WP_ + wpg;
#pragma unroll
    for (int i = 0; i < 5; ++i) {
        const size_t o = ob0 + (size_t)i * WP_;
        Bq[o] = make_uint4(h2u(S0), h2u(S1), h2u(S2), h2u(S3));
        Bs[o] = h2u(S4);
        if (i < 4) {
            uint4 q; unsigned sv;
            rowsum(rb + 9 + i, q, sv);
            const uint4  oq = (i == 0) ? w0q : (i == 1) ? w1q : (i == 2) ? w2q : w3q;
            const unsigned os = (i == 0) ? w0s : (i == 1) ? w1s : (i == 2) ? w2s : w3s;
            S0 = __hadd2(__hsub2(S0, u2h(oq.x)), u2h(q.x));
            S1 = __hadd2(__hsub2(S1, u2h(oq.y)), u2h(q.y));
            S2 = __hadd2(__hsub2(S2, u2h(oq.z)), u2h(q.z));
            S3 = __hadd2(__hsub2(S3, u2h(oq.w)), u2h(q.w));
            S4 = __hadd2(__hsub2(S4, u2h(os)),   u2h(sv));
        }
    }
}

// ------- pass3: D-axis box sum + cc + reduce + ticket finalize -------------
__global__ __launch_bounds__(256) void ncc_pass3(const uint4* __restrict__ Bq,
                                                 const unsigned* __restrict__ Bs,
                                                 float* __restrict__ acc,
                                                 unsigned* __restrict__ ctr,
                                                 float* __restrict__ out) {
    const int orig = (blockIdx.x % NXCD) * (NBLK3 / NXCD) + blockIdx.x / NXCD;
    const int k = orig & 7;                        // d-chunk (fast)
    const int ppBlk = orig >> 3;                   // pp-group (slow)
    const int pp = ppBlk * 256 + threadIdx.x;
    const int d0 = k * CH3;
    const uint4* bq = Bq + pp;
    const unsigned* bs = Bs + pp;

    uint4 fq[9]; unsigned fs[9];
    float2 S[5] = {{0,0},{0,0},{0,0},{0,0},{0,0}};
#pragma unroll
    for (int j = 0; j < 9; ++j) {
        int dd = d0 - 4 + j;
        uint4 q = make_uint4(0u, 0u, 0u, 0u); unsigned sv = 0u;
        if ((unsigned)dd < (unsigned)D_) {
            q = bq[(size_t)dd * HWP_]; sv = bs[(size_t)dd * HWP_];
        }
        fq[j] = q; fs[j] = sv;
        addU(S, q, sv);
    }
    float sum = 0.f;
#pragma unroll
    for (int i = 0; i < CH3; ++i) {
        {
            float cr = S[4].x - S[1].x * S[0].x * WIN_INV;
            float Iv = S[2].x - S[0].x * S[0].x * WIN_INV;
            float Jv = S[3].x - S[1].x * S[1].x * WIN_INV;
            sum += cr * cr / (Iv * Jv + 1e-5f);
        }
        {
            float cr = S[4].y - S[1].y * S[0].y * WIN_INV;
            float Iv = S[2].y - S[0].y * S[0].y * WIN_INV;
            float Jv = S[3].y - S[1].y * S[1].y * WIN_INV;
            sum += cr * cr / (Iv * Jv + 1e-5f);
        }
        if (i + 1 < CH3) {
            int dl = d0 + i + 5;
            uint4 q = make_uint4(0u, 0u, 0u, 0u); unsigned sv = 0u;
            if (dl < D_) { q = bq[(size_t)dl * HWP_]; sv = bs[(size_t)dl * HWP_]; }
            subU(S, fq[0], fs[0]);
            addU(S, q, sv);
#pragma unroll
            for (int j = 0; j < 8; ++j) { fq[j] = fq[j + 1]; fs[j] = fs[j + 1]; }
            fq[8] = q; fs[8] = sv;
        }
    }

    for (int off = 32; off; off >>= 1) sum += __shfl_down(sum, off, 64);
    __shared__ float wsum[4];
    const int lane = threadIdx.x & 63, wv = threadIdx.x >> 6;
    if (lane == 0) wsum[wv] = sum;
    __syncthreads();
    if (threadIdx.x == 0) {
        float old = atomicAdd(acc, wsum[0] + wsum[1] + wsum[2] + wsum[3]);
        asm volatile("" :: "v"(old));   // consume: forces completion before ticket
        unsigned t = atomicAdd(ctr, 1u);
        if (t == NBLK3 - 1) {           // last block: all acc-adds completed
            float tot = atomicAdd(acc, 0.0f);
            out[0] = 1.0f - tot * (1.0f / (float)N_);
        }
    }
}

extern "C" void kernel_launch(void* const* d_in, const int* in_sizes, int n_in,
                              void* d_out, int out_size, void* d_ws, size_t ws_size,
                              hipStream_t stream) {
    const float* I = (const float*)d_in[0];   // y_true
    const float* J = (const float*)d_in[1];   // y_pred
    char* w = (char*)d_ws;
    uint4* Bq = (uint4*)w;                                 // 31.46 MB
    unsigned* Bs = (unsigned*)(w + (size_t)NP_ * 16);      // 7.86 MB
    float* acc = (float*)(w + (size_t)NP_ * 20);
    unsigned* ctr = (unsigned*)(w + (size_t)NP_ * 20 + 4);
    float* out = (float*)d_out;

    ncc_k12<<<NBLK12, 256, 0, stream>>>(I, J, Bq, Bs, acc, ctr);
    ncc_pass3<<<NBLK3, 256, 0, stream>>>(Bq, Bs, acc, ctr, out);
}